// Round 10
// baseline (552.449 us; speedup 1.0000x reference)
//
#include <hip/hip_runtime.h>

// GAT layer, N=8192, H=4, d=128.
// softmax_j(src_i + tgt_j) masked == adj-normalized w_j = exp(tgt_j); src cancels:
//   out[i,d] = 0.25 * sum_h ( (adj @ (w_h*ht_h))[i,d] / (adj @ w_h)[i] )
// Pipeline:
//   kP: pack_adj: adj int32 -> bitmask adjb [8192][256 u32] (8 MB), ~45us HBM.
//   k0: Wt = W^T
//   k1: HT = leakyrelu(h @ W) bf16 MFMA        [8192 x 512]
//   k2: build Yt fragment-major (r8 layout): tile (R=row/16, T=k/32) is a
//       1KB block [q][r][e] bf16; rows 0..511 = w*ht, 512..515 = w.
//   k3: adj_gemm v9b: BM=128, BN=512(+den), 8 waves, grid (4,64) kh->XCD
//       pinned. ZERO LDS, ZERO barriers: A fragments expanded in-register
//       from the bitmask (VALU expand overlaps B-load latency); B direct
//       global->reg coalesced 1KB fragments (L2-resident). Waves fully
//       independent -> compiler pipelines across steps.
//       (r9 bug fixed: B tile base is w0 = kh*64, NOT w0*2 -- T and the
//        bitmask dword index are the same k/32 unit.)
//   k4: out = 0.25 * sum_g (sum_kh C_kh)[i,512g+d] / (sum_kh S_kh)[g,i]
// ws ~93 MB: Wt 0.5M | HT 8M | Yt 8.65M | C 64M | S 0.5M | adjb 8M

typedef unsigned short u16;
typedef unsigned int u32;
using bf16x8 = __attribute__((ext_vector_type(8))) short;
using f32x4  = __attribute__((ext_vector_type(4))) float;
using i32x4  = __attribute__((ext_vector_type(4))) int;

__device__ __forceinline__ u16 f2bf(float f) {
  u32 u = __float_as_uint(f);
  return (u16)((u + 0x7FFFu + ((u >> 16) & 1u)) >> 16);  // RNE
}
__device__ __forceinline__ float bf2f(u16 u) {
  return __uint_as_float(((u32)u) << 16);
}

// ---------------- kP: pack adj int32 -> bitmask [8192][256 u32] -------------
// Thread owns u32 (row, w): reads 32 consecutive ints (128 B), writes 1 u32.
__global__ void pack_adj(const int* __restrict__ adj, u32* __restrict__ adjb) {
  int idx = blockIdx.x * 256 + threadIdx.x;        // 2M threads = 8192 blocks
  const int* p = adj + (size_t)idx * 32;
  u32 m = 0;
#pragma unroll
  for (int c = 0; c < 8; ++c) {
    i32x4 v = __builtin_nontemporal_load((const i32x4*)(p + 4 * c));
    m |= (v[0] != 0 ? 1u : 0u) << (4 * c);
    m |= (v[1] != 0 ? 1u : 0u) << (4 * c + 1);
    m |= (v[2] != 0 ? 1u : 0u) << (4 * c + 2);
    m |= (v[3] != 0 ? 1u : 0u) << (4 * c + 3);
  }
  adjb[idx] = m;
}

// ---------------- k0: transpose W [256][512] -> Wt [512][256] ----------------
__global__ void transpose_w(const float* __restrict__ W, float* __restrict__ Wt) {
  __shared__ float tile[32][33];
  int cb = blockIdx.x * 32, kb = blockIdx.y * 32;
  int tc = threadIdx.x & 31, tr = threadIdx.x >> 5;
  for (int p = 0; p < 32; p += 8)
    tile[tr + p][tc] = W[(size_t)(kb + tr + p) * 512 + cb + tc];
  __syncthreads();
  for (int p = 0; p < 32; p += 8)
    Wt[(size_t)(cb + tr + p) * 256 + kb + tc] = tile[tc][tr + p];
}

// ---------------- k1: HT = leaky(h @ W), bf16 out [8192][512] ----------------
__global__ void ht_gemm(const float* __restrict__ h, const float* __restrict__ Wt,
                        u16* __restrict__ HT) {
  __shared__ __align__(16) u16 Abuf[128 * 40];
  __shared__ __align__(16) u16 Bbuf[128 * 40];
  int tid = threadIdx.x;
  int cb = blockIdx.x, rb = blockIdx.y;
  int r0 = rb * 128, c0 = cb * 128;
  int lane = tid & 63, wv = tid >> 6;
  int wr = wv >> 1, wc = wv & 1;
  int mrow = lane & 15, q = lane >> 4;
  int ch = tid & 7, m0 = tid >> 3;

  f32x4 acc[4][4];
#pragma unroll
  for (int i = 0; i < 4; i++)
#pragma unroll
    for (int j = 0; j < 4; j++) acc[i][j] = f32x4{0.f, 0.f, 0.f, 0.f};

  for (int kt = 0; kt < 256; kt += 32) {
    __syncthreads();
#pragma unroll
    for (int mp = 0; mp < 128; mp += 32) {
      int m = m0 + mp;
      float4 v = *(const float4*)(&h[(size_t)(r0 + m) * 256 + kt + ch * 4]);
      uint2 p;
      p.x = (u32)f2bf(v.x) | ((u32)f2bf(v.y) << 16);
      p.y = (u32)f2bf(v.z) | ((u32)f2bf(v.w) << 16);
      *(uint2*)(&Abuf[m * 40 + ch * 4]) = p;
      float4 u = *(const float4*)(&Wt[(size_t)(c0 + m) * 256 + kt + ch * 4]);
      uint2 r;
      r.x = (u32)f2bf(u.x) | ((u32)f2bf(u.y) << 16);
      r.y = (u32)f2bf(u.z) | ((u32)f2bf(u.w) << 16);
      *(uint2*)(&Bbuf[m * 40 + ch * 4]) = r;
    }
    __syncthreads();
    bf16x8 af[4], bfv[4];
#pragma unroll
    for (int i = 0; i < 4; i++)
      af[i] = *(const bf16x8*)(&Abuf[(wr * 64 + i * 16 + mrow) * 40 + q * 8]);
#pragma unroll
    for (int j = 0; j < 4; j++)
      bfv[j] = *(const bf16x8*)(&Bbuf[(wc * 64 + j * 16 + mrow) * 40 + q * 8]);
#pragma unroll
    for (int i = 0; i < 4; i++)
#pragma unroll
      for (int j = 0; j < 4; j++)
        acc[i][j] = __builtin_amdgcn_mfma_f32_16x16x32_bf16(af[i], bfv[j], acc[i][j], 0, 0, 0);
  }
#pragma unroll
  for (int i = 0; i < 4; i++)
#pragma unroll
    for (int j = 0; j < 4; j++)
#pragma unroll
      for (int r = 0; r < 4; r++) {
        int gi = r0 + wr * 64 + i * 16 + q * 4 + r;
        int gc = c0 + wc * 64 + j * 16 + mrow;
        float v = acc[i][j][r];
        v = v >= 0.f ? v : 0.1f * v;
        HT[(size_t)gi * 512 + gc] = f2bf(v);
      }
}

// ---------------- k2: build Yt (fragment-major) ----------------
// Yt u16 index for (row c, graph-node j):
//   ((c/16)*256 + j/32)*512 + ((j%32)/8)*128 + (c%16)*8 + (j%8)
__global__ void build_yt(const u16* __restrict__ HT, const float* __restrict__ a,
                         u16* __restrict__ Yt) {
  __shared__ u16 sht[32][528];
  __shared__ float swv[32 * 4];
  __shared__ float sa[512];
  int t = threadIdx.x;
  int j0 = blockIdx.x * 32;
  for (int i = t; i < 512; i += 256) {
    int g = i >> 7, d = i & 127;
    sa[i] = a[g * 256 + 128 + d];
  }
#pragma unroll
  for (int p = 0; p < 8; ++p) {
    int el = t + 256 * p;                 // 2048 uint4 slots: 32 rows x 64
    int row = el >> 6, col8 = el & 63;
    *(uint4*)(&sht[row][col8 * 8]) = *(const uint4*)(&HT[(size_t)(j0 + row) * 512 + col8 * 8]);
  }
  __syncthreads();
  if (t < 128) {
    int jl = t >> 2, g = t & 3;
    float acc = 0.f;
#pragma unroll
    for (int d8 = 0; d8 < 16; ++d8) {
      bf16x8 v = *(const bf16x8*)(&sht[jl][g * 128 + d8 * 8]);
#pragma unroll
      for (int u = 0; u < 8; ++u)
        acc += bf2f((u16)v[u]) * sa[g * 128 + d8 * 8 + u];
    }
    swv[jl * 4 + g] = __expf(acc);
  }
  __syncthreads();
  int oj = (t & 3) * 8, oc = t >> 2;      // oj = q*8 (j-octet), oc among 64 c
  size_t T = j0 >> 5;
  for (int pass = 0; pass < 9; ++pass) {
    int c = pass * 64 + oc;
    if (c >= 528) break;
    u32 pk[4] = {0u, 0u, 0u, 0u};
    if (c < 512) {
      int g = c >> 7;
#pragma unroll
      for (int u = 0; u < 4; ++u) {
        int j = oj + 2 * u;
        float v0 = bf2f(sht[j][c]) * swv[j * 4 + g];
        float v1 = bf2f(sht[j + 1][c]) * swv[(j + 1) * 4 + g];
        pk[u] = (u32)f2bf(v0) | ((u32)f2bf(v1) << 16);
      }
    } else if (c < 516) {
      int g = c - 512;
#pragma unroll
      for (int u = 0; u < 4; ++u) {
        int j = oj + 2 * u;
        float v0 = swv[j * 4 + g];
        float v1 = swv[(j + 1) * 4 + g];
        pk[u] = (u32)f2bf(v0) | ((u32)f2bf(v1) << 16);
      }
    }
    size_t dst = ((size_t)(c >> 4) * 256 + T) * 512 + (size_t)(oj >> 3) * 128 + (c & 15) * 8;
    *(uint4*)(&Yt[dst]) = make_uint4(pk[0], pk[1], pk[2], pk[3]);
  }
}

// ---------------- k3: adj GEMM v9b -- bitmask A, no LDS, no barriers -------
// grid (4, 64) = (kh, rb): XCD = linear%8 in {kh, kh+4} -> each XCD's L2
// holds ONE 2.1 MB Yt quarter. 512 threads = 8 waves (2 wr x 4 wc).
// Per step t: issue 8 coalesced 1KB B-fragment loads; load 4 mask dwords;
// expand bits->bf16 A fragments in registers (VALU covers B latency);
// 36 MFMAs. No __syncthreads anywhere in the loop -- waves independent.
__global__ __launch_bounds__(512) void adj_gemm(const u32* __restrict__ adjb,
                                                const u16* __restrict__ Yt,
                                                float* __restrict__ C,
                                                float* __restrict__ S) {
  int tid = threadIdx.x;
  int rb = blockIdx.y, kh = blockIdx.x;             // kh fastest -> XCD pin
  int r0 = rb * 128;
  int w0 = kh * 64;                                 // 2048 k = 64 u32 dwords = 64 tiles
  int lane = tid & 63, wv = tid >> 6;
  int wr = wv >> 2, wc = wv & 3;
  int mrow = lane & 15, q = lane >> 4;
  u32 sh = q * 8;
  bool do_den = (wc == 0);
  // mask base: row = r0 + wr*64 + i*16 + mrow, dword w0 + t
  const u32* mbase = adjb + (size_t)(r0 + wr * 64 + mrow) * 256 + w0;
  // B fragment bases: frag (j, t) at ybase + (j*256 + t)*512 u16.
  // T and w share the unit k/32 -> tile base offset is w0 (r9 bug: was w0*2).
  const u16* ybase = Yt + ((size_t)(wc * 8) * 256 + (size_t)w0) * 512 + (size_t)lane * 8;
  const u16* dbase = Yt + ((size_t)32 * 256 + (size_t)w0) * 512 + (size_t)lane * 8;

  f32x4 acc[4][8];
#pragma unroll
  for (int i = 0; i < 4; i++)
#pragma unroll
    for (int j = 0; j < 8; j++) acc[i][j] = f32x4{0.f, 0.f, 0.f, 0.f};
  f32x4 accD[4];
#pragma unroll
  for (int i = 0; i < 4; i++) accD[i] = f32x4{0.f, 0.f, 0.f, 0.f};

  for (int t = 0; t < 64; ++t) {
    // ---- B fragments: coalesced 1KB loads (L2-hot via XCD pin) ----
    bf16x8 bfv[8];
#pragma unroll
    for (int j = 0; j < 8; j++)
      bfv[j] = *(const bf16x8*)(ybase + ((size_t)j * 256 + t) * 512);
    bf16x8 bd;
    if (do_den) bd = *(const bf16x8*)(dbase + (size_t)t * 512);
    // ---- A fragments: bitmask -> bf16 expand (pure VALU, covers B lat) ----
    bf16x8 af[4];
#pragma unroll
    for (int i = 0; i < 4; i++) {
      u32 m = mbase[(size_t)i * 4096 + t];          // 16 rows * 256 dwords
      u32 b = (m >> sh) & 0xFFu;
      u32 w[4];
#pragma unroll
      for (int e = 0; e < 4; ++e)
        w[e] = (((b >> (2 * e)) & 1u) ? 0x3F80u : 0u) |
               (((b >> (2 * e + 1)) & 1u) ? 0x3F800000u : 0u);
      af[i] = *(const bf16x8*)&w[0];
    }
    // ---- MFMAs (bfv consumed in j-order -> counted vmcnt) ----
    __builtin_amdgcn_s_setprio(1);
#pragma unroll
    for (int j = 0; j < 8; j++)
#pragma unroll
      for (int i = 0; i < 4; i++)
        acc[i][j] = __builtin_amdgcn_mfma_f32_16x16x32_bf16(af[i], bfv[j], acc[i][j], 0, 0, 0);
    if (do_den) {
#pragma unroll
      for (int i = 0; i < 4; i++)
        accD[i] = __builtin_amdgcn_mfma_f32_16x16x32_bf16(af[i], bd, accD[i], 0, 0, 0);
    }
    __builtin_amdgcn_s_setprio(0);
  }

  float* Ck = C + (size_t)kh * 8192 * 512;
#pragma unroll
  for (int i = 0; i < 4; i++)
#pragma unroll
    for (int j = 0; j < 8; j++)
#pragma unroll
      for (int r = 0; r < 4; r++) {
        int gi = r0 + wr * 64 + i * 16 + q * 4 + r;
        int gc = wc * 128 + j * 16 + mrow;
        Ck[(size_t)gi * 512 + gc] = acc[i][j][r];
      }
  if (do_den && mrow < 4) {
    float* Sk = S + (size_t)kh * 4 * 8192;
#pragma unroll
    for (int i = 0; i < 4; i++)
#pragma unroll
      for (int r = 0; r < 4; r++) {
        int gi = r0 + wr * 64 + i * 16 + q * 4 + r;
        Sk[(size_t)mrow * 8192 + gi] = accD[i][r];
      }
  }
}

// ---------------- k4: combine K-split + heads ----------------
__global__ void finalize_gat(const float* __restrict__ C, const float* __restrict__ S,
                             float* __restrict__ out) {
  int idx = blockIdx.x * 256 + threadIdx.x;
  int i = idx >> 7, d = idx & 127;
  float s = 0.f;
#pragma unroll
  for (int g = 0; g < 4; ++g) {
    float num = 0.f, den = 0.f;
#pragma unroll
    for (int kh = 0; kh < 4; ++kh) {
      num += C[(size_t)kh * 8192 * 512 + (size_t)i * 512 + g * 128 + d];
      den += S[(size_t)kh * 4 * 8192 + (size_t)g * 8192 + i];
    }
    s += num / den;
  }
  out[idx] = 0.25f * s;
}

extern "C" void kernel_launch(void* const* d_in, const int* in_sizes, int n_in,
                              void* d_out, int out_size, void* d_ws, size_t ws_size,
                              hipStream_t stream) {
  const float* h   = (const float*)d_in[0];
  const int*   adj = (const int*)d_in[1];
  const float* W   = (const float*)d_in[2];
  const float* a   = (const float*)d_in[3];
  float* out = (float*)d_out;
  char* ws = (char*)d_ws;
  // ws: Wt 0.5M | HT 8M | Yt 8.65M | C 64M (4 x 16M) | S 0.5M | adjb 8M
  float* Wt = (float*)(ws + 0);
  u16*   HT = (u16*)(ws + 524288);
  u16*   Yt = (u16*)(ws + 8912896);
  float* C  = (float*)(ws + 17563648);
  float* S  = (float*)(ws + 84672512);
  u32*  adjb = (u32*)(ws + 84803584);

  pack_adj<<<dim3(8192), 256, 0, stream>>>(adj, adjb);
  transpose_w<<<dim3(16, 8), 256, 0, stream>>>(W, Wt);
  ht_gemm<<<dim3(4, 64), 256, 0, stream>>>(h, Wt, HT);
  build_yt<<<dim3(256), 256, 0, stream>>>(HT, a, Yt);
  adj_gemm<<<dim3(4, 64), 512, 0, stream>>>(adjb, Yt, C, S);
  finalize_gat<<<dim3(4096), 256, 0, stream>>>(C, S, out);
}

// Round 11
// 521.383 us; speedup vs baseline: 1.0596x; 1.0596x over previous
//
#include <hip/hip_runtime.h>

// GAT layer, N=8192, H=4, d=128.
// softmax_j(src_i + tgt_j) masked == adj-normalized w_j = exp(tgt_j); src cancels:
//   out[i,d] = 0.25 * sum_h ( (adj @ (w_h*ht_h))[i,d] / (adj @ w_h)[i] )
// Pipeline:
//   kP: pack_adj: adj int32 -> bitmask adjb [8192][256 u32] (8 MB).
//   k0: Wt = W^T
//   k1: HT = leakyrelu(h @ W) bf16 MFMA        [8192 x 512]
//   k2: build_yt bf16 [528][8192] row-major (grid 256, 32-j slabs)
//   k3: adj_gemm v11: BM=128, BN=256(+den), grid (8,64): bx = kh + 4*cs
//       (kh->XCD pin; per-XCD B set 1.1 MB L2-resident). 256 threads =
//       4 waves (2wr x 2wc), wave tile 64x128. LDS 68.6 KB -> TWO blocks
//       per CU = two independent barrier domains (r1-proven 2x fill).
//       B: 2-ahead GLD16 tri-buffer, counted vmcnt(4|5) per step (tile
//       t+2 survives the barrier). A: bitmask dword -> bf16 expand in
//       the staging path (no adj HBM stream in the gemm), XOR-swizzled
//       LDS dbuf. One lgkm-wait + barrier per step.
//   k4: out = 0.25 * sum_g (sum_kh C_kh)[i,512g+d] / (sum_kh S_kh)[g,i]
// ws ~93 MB: Wt 0.5M | HT 8M | Yt 8.65M | C 64M | S 0.5M | adjb 8M

typedef unsigned short u16;
typedef unsigned int u32;
using bf16x8 = __attribute__((ext_vector_type(8))) short;
using f32x4  = __attribute__((ext_vector_type(4))) float;
using i32x4  = __attribute__((ext_vector_type(4))) int;

typedef const void __attribute__((address_space(1))) gas_void;
typedef void __attribute__((address_space(3))) las_void;
#define GLD16(g, l) __builtin_amdgcn_global_load_lds((gas_void*)(g), (las_void*)(l), 16, 0, 0)

__device__ __forceinline__ u16 f2bf(float f) {
  u32 u = __float_as_uint(f);
  return (u16)((u + 0x7FFFu + ((u >> 16) & 1u)) >> 16);  // RNE
}
__device__ __forceinline__ float bf2f(u16 u) {
  return __uint_as_float(((u32)u) << 16);
}

// ---------------- kP: pack adj int32 -> bitmask [8192][256 u32] -------------
__global__ void pack_adj(const int* __restrict__ adj, u32* __restrict__ adjb) {
  int idx = blockIdx.x * 256 + threadIdx.x;        // 2M threads
  const int* p = adj + (size_t)idx * 32;
  u32 m = 0;
#pragma unroll
  for (int c = 0; c < 8; ++c) {
    i32x4 v = __builtin_nontemporal_load((const i32x4*)(p + 4 * c));
    m |= (v[0] != 0 ? 1u : 0u) << (4 * c);
    m |= (v[1] != 0 ? 1u : 0u) << (4 * c + 1);
    m |= (v[2] != 0 ? 1u : 0u) << (4 * c + 2);
    m |= (v[3] != 0 ? 1u : 0u) << (4 * c + 3);
  }
  adjb[idx] = m;
}

// ---------------- k0: transpose W [256][512] -> Wt [512][256] ----------------
__global__ void transpose_w(const float* __restrict__ W, float* __restrict__ Wt) {
  __shared__ float tile[32][33];
  int cb = blockIdx.x * 32, kb = blockIdx.y * 32;
  int tc = threadIdx.x & 31, tr = threadIdx.x >> 5;
  for (int p = 0; p < 32; p += 8)
    tile[tr + p][tc] = W[(size_t)(kb + tr + p) * 512 + cb + tc];
  __syncthreads();
  for (int p = 0; p < 32; p += 8)
    Wt[(size_t)(cb + tr + p) * 256 + kb + tc] = tile[tc][tr + p];
}

// ---------------- k1: HT = leaky(h @ W), bf16 out [8192][512] ----------------
__global__ void ht_gemm(const float* __restrict__ h, const float* __restrict__ Wt,
                        u16* __restrict__ HT) {
  __shared__ __align__(16) u16 Abuf[128 * 40];
  __shared__ __align__(16) u16 Bbuf[128 * 40];
  int tid = threadIdx.x;
  int cb = blockIdx.x, rb = blockIdx.y;
  int r0 = rb * 128, c0 = cb * 128;
  int lane = tid & 63, wv = tid >> 6;
  int wr = wv >> 1, wc = wv & 1;
  int mrow = lane & 15, q = lane >> 4;
  int ch = tid & 7, m0 = tid >> 3;

  f32x4 acc[4][4];
#pragma unroll
  for (int i = 0; i < 4; i++)
#pragma unroll
    for (int j = 0; j < 4; j++) acc[i][j] = f32x4{0.f, 0.f, 0.f, 0.f};

  for (int kt = 0; kt < 256; kt += 32) {
    __syncthreads();
#pragma unroll
    for (int mp = 0; mp < 128; mp += 32) {
      int m = m0 + mp;
      float4 v = *(const float4*)(&h[(size_t)(r0 + m) * 256 + kt + ch * 4]);
      uint2 p;
      p.x = (u32)f2bf(v.x) | ((u32)f2bf(v.y) << 16);
      p.y = (u32)f2bf(v.z) | ((u32)f2bf(v.w) << 16);
      *(uint2*)(&Abuf[m * 40 + ch * 4]) = p;
      float4 u = *(const float4*)(&Wt[(size_t)(c0 + m) * 256 + kt + ch * 4]);
      uint2 r;
      r.x = (u32)f2bf(u.x) | ((u32)f2bf(u.y) << 16);
      r.y = (u32)f2bf(u.z) | ((u32)f2bf(u.w) << 16);
      *(uint2*)(&Bbuf[m * 40 + ch * 4]) = r;
    }
    __syncthreads();
    bf16x8 af[4], bfv[4];
#pragma unroll
    for (int i = 0; i < 4; i++)
      af[i] = *(const bf16x8*)(&Abuf[(wr * 64 + i * 16 + mrow) * 40 + q * 8]);
#pragma unroll
    for (int j = 0; j < 4; j++)
      bfv[j] = *(const bf16x8*)(&Bbuf[(wc * 64 + j * 16 + mrow) * 40 + q * 8]);
#pragma unroll
    for (int i = 0; i < 4; i++)
#pragma unroll
      for (int j = 0; j < 4; j++)
        acc[i][j] = __builtin_amdgcn_mfma_f32_16x16x32_bf16(af[i], bfv[j], acc[i][j], 0, 0, 0);
  }
#pragma unroll
  for (int i = 0; i < 4; i++)
#pragma unroll
    for (int j = 0; j < 4; j++)
#pragma unroll
      for (int r = 0; r < 4; r++) {
        int gi = r0 + wr * 64 + i * 16 + q * 4 + r;
        int gc = c0 + wc * 64 + j * 16 + mrow;
        float v = acc[i][j][r];
        v = v >= 0.f ? v : 0.1f * v;
        HT[(size_t)gi * 512 + gc] = f2bf(v);
      }
}

// ---------------- k2: build Yt [528][8192] bf16 (row-major, grid 256) -------
__global__ void build_yt(const u16* __restrict__ HT, const float* __restrict__ a,
                         u16* __restrict__ Yt) {
  __shared__ u16 sht[32][528];
  __shared__ float swv[32 * 4];
  __shared__ float sa[512];
  int t = threadIdx.x;
  int j0 = blockIdx.x * 32;
  for (int i = t; i < 512; i += 256) {
    int g = i >> 7, d = i & 127;
    sa[i] = a[g * 256 + 128 + d];
  }
#pragma unroll
  for (int p = 0; p < 8; ++p) {
    int el = t + 256 * p;
    int row = el >> 6, col8 = el & 63;
    *(uint4*)(&sht[row][col8 * 8]) = *(const uint4*)(&HT[(size_t)(j0 + row) * 512 + col8 * 8]);
  }
  __syncthreads();
  if (t < 128) {
    int jl = t >> 2, g = t & 3;
    float acc = 0.f;
#pragma unroll
    for (int d8 = 0; d8 < 16; ++d8) {
      bf16x8 v = *(const bf16x8*)(&sht[jl][g * 128 + d8 * 8]);
#pragma unroll
      for (int u = 0; u < 8; ++u)
        acc += bf2f((u16)v[u]) * sa[g * 128 + d8 * 8 + u];
    }
    swv[jl * 4 + g] = __expf(acc);
  }
  __syncthreads();
  int oj = (t & 3) * 8, oc = t >> 2;
  for (int pass = 0; pass < 9; ++pass) {
    int c = pass * 64 + oc;
    if (c >= 528) break;
    u32 pk[4] = {0u, 0u, 0u, 0u};
    if (c < 512) {
      int g = c >> 7;
#pragma unroll
      for (int u = 0; u < 4; ++u) {
        int j = oj + 2 * u;
        float v0 = bf2f(sht[j][c]) * swv[j * 4 + g];
        float v1 = bf2f(sht[j + 1][c]) * swv[(j + 1) * 4 + g];
        pk[u] = (u32)f2bf(v0) | ((u32)f2bf(v1) << 16);
      }
    } else if (c < 516) {
      int g = c - 512;
#pragma unroll
      for (int u = 0; u < 4; ++u) {
        int j = oj + 2 * u;
        float v0 = swv[j * 4 + g];
        float v1 = swv[(j + 1) * 4 + g];
        pk[u] = (u32)f2bf(v0) | ((u32)f2bf(v1) << 16);
      }
    }
    *(uint4*)(&Yt[(size_t)c * 8192 + j0 + oj]) = make_uint4(pk[0], pk[1], pk[2], pk[3]);
  }
}

// ---------------- k3: adj GEMM v11 -- col-split, 2 blocks/CU ----------------
// grid (8, 64): bx = kh + 4*cs -> XCD = bx (pin); by = rb.
// 256 threads = 4 waves (wr = wv>>1 in {0,1}, wc = wv&1 in {0,1}).
// Wave tile 64x128 of the 128x256 block tile. K = 2048 (kh quarter), 64 steps.
// B: 17 tiles x 16 rows (16 col-tiles + den) staged 2-ahead via GLD16
//    (src-octet swizzle), tri-buffer; counted vmcnt(4|5) keeps t+2 in flight.
// A: 1 bitmask dword / thread / step -> 16 bf16 expand -> swizzled LDS dbuf.
__global__ __launch_bounds__(256, 2) void adj_gemm(const u32* __restrict__ adjb,
                                                   const u16* __restrict__ Yt,
                                                   float* __restrict__ C,
                                                   float* __restrict__ S) {
  __shared__ __align__(16) u16 Bbuf[3][272 * 32];   // 51 KB
  __shared__ __align__(16) u16 Abuf[2][128 * 32];   // 16 KB
  int tid = threadIdx.x;
  int bx = blockIdx.x, rb = blockIdx.y;
  int kh = bx & 3, cs = bx >> 2;
  int r0 = rb * 128, k0 = kh * 2048, w0 = kh * 64;
  int lane = tid & 63, wv = tid >> 6;
  int wr = wv >> 1, wc = wv & 1;
  int mrow = lane & 15, q = lane >> 4;
  int qs = q ^ ((mrow >> 1) & 3);                   // swizzled read slot
  // A staging: thread -> (row am = tid>>1, k-half ah = tid&1)
  int am = tid >> 1, ah = tid & 1;
  int arx = (am >> 1) & 3;
  int as0 = am * 32 + ((ah * 2) ^ arx) * 8;         // two swizzled slots
  int as1 = am * 32 + ((ah * 2 + 1) ^ arx) * 8;
  const u32* ab = adjb + (size_t)(r0 + am) * 256 + w0;
  // B staging lane pattern
  int brow = lane >> 2;
  int bq = (lane & 3) ^ ((lane >> 3) & 3);          // pre-swizzled src octet
  bool den_stage = (cs == 0 && wv == 0);
  bool den_mfma  = (cs == 0 && wc == 0);

  f32x4 acc[4][8];
#pragma unroll
  for (int i = 0; i < 4; i++)
#pragma unroll
    for (int j = 0; j < 8; j++) acc[i][j] = f32x4{0.f, 0.f, 0.f, 0.f};
  f32x4 accD[4];
#pragma unroll
  for (int i = 0; i < 4; i++) accD[i] = f32x4{0.f, 0.f, 0.f, 0.f};

#define EXPANDA(DST, M)                                                      \
  {                                                                          \
    u32 hh = ((M) >> (ah * 16)) & 0xFFFFu;                                   \
    u32 b0 = hh & 0xFFu, b1 = hh >> 8;                                       \
    uint4 p0, p1;                                                            \
    p0.x = ((b0 & 1u) ? 0x3F80u : 0u) | ((b0 & 2u) ? 0x3F800000u : 0u);      \
    p0.y = ((b0 & 4u) ? 0x3F80u : 0u) | ((b0 & 8u) ? 0x3F800000u : 0u);      \
    p0.z = ((b0 & 16u) ? 0x3F80u : 0u) | ((b0 & 32u) ? 0x3F800000u : 0u);    \
    p0.w = ((b0 & 64u) ? 0x3F80u : 0u) | ((b0 & 128u) ? 0x3F800000u : 0u);   \
    p1.x = ((b1 & 1u) ? 0x3F80u : 0u) | ((b1 & 2u) ? 0x3F800000u : 0u);      \
    p1.y = ((b1 & 4u) ? 0x3F80u : 0u) | ((b1 & 8u) ? 0x3F800000u : 0u);      \
    p1.z = ((b1 & 16u) ? 0x3F80u : 0u) | ((b1 & 32u) ? 0x3F800000u : 0u);    \
    p1.w = ((b1 & 64u) ? 0x3F80u : 0u) | ((b1 & 128u) ? 0x3F800000u : 0u);   \
    *(uint4*)((DST) + as0) = p0;                                             \
    *(uint4*)((DST) + as1) = p1;                                             \
  }
#define STAGE_B(DB, KT)                                                      \
  {                                                                          \
    _Pragma("unroll") for (int p = 0; p < 4; ++p)                            \
        GLD16(&Yt[(size_t)(cs * 256 + (wv + 4 * p) * 16 + brow) * 8192 + (KT) + bq * 8], \
              (DB) + ((wv + 4 * p) * 16) * 32);                              \
    if (den_stage)                                                           \
      GLD16(&Yt[(size_t)(512 + brow) * 8192 + (KT) + bq * 8], (DB) + 256 * 32); \
  }
#define WAIT_KEEP()                                                          \
  {                                                                          \
    if (den_stage) asm volatile("s_waitcnt vmcnt(5)" ::: "memory");          \
    else           asm volatile("s_waitcnt vmcnt(4)" ::: "memory");          \
  }

  // ---- prologue: m(0) -> A buf0; GLD16 tiles 0,1 -> Bbuf[0],Bbuf[1] ----
  {
    u32 m0 = ab[0];
    STAGE_B(&Bbuf[0][0], k0);
    STAGE_B(&Bbuf[1][0], k0 + 32);
    EXPANDA(&Abuf[0][0], m0);        // m0 use drains it; GLD16s stay
    WAIT_KEEP();                     // retire tile0; tile1 in flight
    asm volatile("s_waitcnt lgkmcnt(0)" ::: "memory");
    __builtin_amdgcn_s_barrier();
  }

  u16 *bcur = &Bbuf[0][0], *bnxt = &Bbuf[1][0], *bnn = &Bbuf[2][0];

  for (int t = 0; t < 64; ++t) {
    u32 m;
    if (t < 63) m = ab[t + 1];                      // tiny L2 load, oldest
    if (t < 62) STAGE_B(bnn, k0 + (t + 2) * 32);
    // ---- compute tile t ----
    bf16x8 af[4], bfv[8];
    const u16* Ab = &Abuf[t & 1][0];
#pragma unroll
    for (int i = 0; i < 4; i++)
      af[i] = *(const bf16x8*)(&Ab[(wr * 64 + i * 16 + mrow) * 32 + qs * 8]);
#pragma unroll
    for (int j = 0; j < 8; j++)
      bfv[j] = *(const bf16x8*)(&bcur[((wc * 8 + j) * 16 + mrow) * 32 + qs * 8]);
    __builtin_amdgcn_s_setprio(1);
#pragma unroll
    for (int i = 0; i < 4; i++)
#pragma unroll
      for (int j = 0; j < 8; j++)
        acc[i][j] = __builtin_amdgcn_mfma_f32_16x16x32_bf16(af[i], bfv[j], acc[i][j], 0, 0, 0);
    if (den_mfma) {
      bf16x8 bd = *(const bf16x8*)(&bcur[(256 + mrow) * 32 + qs * 8]);
#pragma unroll
      for (int i = 0; i < 4; i++)
        accD[i] = __builtin_amdgcn_mfma_f32_16x16x32_bf16(af[i], bd, accD[i], 0, 0, 0);
    }
    __builtin_amdgcn_s_setprio(0);
    // ---- finish staging A(t+1) ----
    if (t < 63) EXPANDA(&Abuf[(t + 1) & 1][0], m);
    // ---- retire tile t+1's GLD16s; t+2's stay in flight ----
    if (t < 62) {
      WAIT_KEEP();
    } else if (t == 62) {
      asm volatile("s_waitcnt vmcnt(0)" ::: "memory");
    }
    if (t < 63) {
      asm volatile("s_waitcnt lgkmcnt(0)" ::: "memory");
      __builtin_amdgcn_s_barrier();
    }
    u16* tb = bcur; bcur = bnxt; bnxt = bnn; bnn = tb;
  }
#undef EXPANDA
#undef STAGE_B
#undef WAIT_KEEP

  float* Ck = C + (size_t)kh * 8192 * 512;
#pragma unroll
  for (int i = 0; i < 4; i++)
#pragma unroll
    for (int j = 0; j < 8; j++)
#pragma unroll
      for (int r = 0; r < 4; r++) {
        int gi = r0 + wr * 64 + i * 16 + q * 4 + r;
        int gc = cs * 256 + wc * 128 + j * 16 + mrow;
        Ck[(size_t)gi * 512 + gc] = acc[i][j][r];
      }
  if (den_mfma && mrow < 4) {
    float* Sk = S + (size_t)kh * 4 * 8192;
#pragma unroll
    for (int i = 0; i < 4; i++)
#pragma unroll
      for (int r = 0; r < 4; r++) {
        int gi = r0 + wr * 64 + i * 16 + q * 4 + r;
        Sk[(size_t)mrow * 8192 + gi] = accD[i][r];
      }
  }
}

// ---------------- k4: combine K-split + heads ----------------
__global__ void finalize_gat(const float* __restrict__ C, const float* __restrict__ S,
                             float* __restrict__ out) {
  int idx = blockIdx.x * 256 + threadIdx.x;
  int i = idx >> 7, d = idx & 127;
  float s = 0.f;
#pragma unroll
  for (int g = 0; g < 4; ++g) {
    float num = 0.f, den = 0.f;
#pragma unroll
    for (int kh = 0; kh < 4; ++kh) {
      num += C[(size_t)kh * 8192 * 512 + (size_t)i * 512 + g * 128 + d];
      den += S[(size_t)kh * 4 * 8192 + (size_t)g * 8192 + i];
    }
    s += num / den;
  }
  out[idx] = 0.25f * s;
}

extern "C" void kernel_launch(void* const* d_in, const int* in_sizes, int n_in,
                              void* d_out, int out_size, void* d_ws, size_t ws_size,
                              hipStream_t stream) {
  const float* h   = (const float*)d_in[0];
  const int*   adj = (const int*)d_in[1];
  const float* W   = (const float*)d_in[2];
  const float* a   = (const float*)d_in[3];
  float* out = (float*)d_out;
  char* ws = (char*)d_ws;
  // ws: Wt 0.5M | HT 8M | Yt 8.65M | C 64M (4 x 16M) | S 0.5M | adjb 8M
  float* Wt = (float*)(ws + 0);
  u16*   HT = (u16*)(ws + 524288);
  u16*   Yt = (u16*)(ws + 8912896);
  float* C  = (float*)(ws + 17563648);
  float* S  = (float*)(ws + 84672512);
  u32*  adjb = (u32*)(ws + 84803584);

  pack_adj<<<dim3(8192), 256, 0, stream>>>(adj, adjb);
  transpose_w<<<dim3(16, 8), 256, 0, stream>>>(W, Wt);
  ht_gemm<<<dim3(4, 64), 256, 0, stream>>>(h, Wt, HT);
  build_yt<<<dim3(256), 256, 0, stream>>>(HT, a, Yt);
  adj_gemm<<<dim3(8, 64), 256, 0, stream>>>(adjb, Yt, C, S);
  finalize_gat<<<dim3(4096), 256, 0, stream>>>(C, S, out);
}

// Round 13
// 454.912 us; speedup vs baseline: 1.2144x; 1.1461x over previous
//
#include <hip/hip_runtime.h>

// GAT layer, N=8192, H=4, d=128.
// softmax_j(src_i + tgt_j) masked == adj-normalized w_j = exp(tgt_j); src cancels:
//   out[i,d] = 0.25 * sum_h ( (adj @ (w_h*ht_h))[i,d] / (adj @ w_h)[i] )
// Pipeline:
//   k0: Wt = W^T
//   k1: HT = leakyrelu(h @ W) bf16 MFMA        [8192 x 512]
//   k2: build_yt bf16 [528][8192] (grid 256, 32-j slabs)
//   k3: adj_gemm v7 (session best): BM=128, BN=512, 8 waves, grid (4,64)
//       kh->XCD pinned. 2-AHEAD GLD16 staging, triple-buffered B LDS,
//       counted vmcnt(4|5) per step (tile t+2 stays in flight across the
//       barrier -- T3/T4). XOR swizzle on A and B (source-octet permute
//       for GLD16, XOR'd 16B-slot on ds_read). nt adj loads.
//   k4: out = 0.25 * sum_g (sum_kh C_kh)[i,512g+d] / (sum_kh S_kh)[g,i]
// ws ~85 MB: Wt 0.5M | HT 8M | Yt 8.65M | C 64M | S 0.5M

typedef unsigned short u16;
typedef unsigned int u32;
using bf16x8 = __attribute__((ext_vector_type(8))) short;
using f32x4  = __attribute__((ext_vector_type(4))) float;
using i32x4  = __attribute__((ext_vector_type(4))) int;

typedef const void __attribute__((address_space(1))) gas_void;
typedef void __attribute__((address_space(3))) las_void;
#define GLD16(g, l) __builtin_amdgcn_global_load_lds((gas_void*)(g), (las_void*)(l), 16, 0, 0)

__device__ __forceinline__ u16 f2bf(float f) {
  u32 u = __float_as_uint(f);
  return (u16)((u + 0x7FFFu + ((u >> 16) & 1u)) >> 16);  // RNE
}
__device__ __forceinline__ float bf2f(u16 u) {
  return __uint_as_float(((u32)u) << 16);
}

// ---------------- k0: transpose W [256][512] -> Wt [512][256] ----------------
__global__ void transpose_w(const float* __restrict__ W, float* __restrict__ Wt) {
  __shared__ float tile[32][33];
  int cb = blockIdx.x * 32, kb = blockIdx.y * 32;
  int tc = threadIdx.x & 31, tr = threadIdx.x >> 5;
  for (int p = 0; p < 32; p += 8)
    tile[tr + p][tc] = W[(size_t)(kb + tr + p) * 512 + cb + tc];
  __syncthreads();
  for (int p = 0; p < 32; p += 8)
    Wt[(size_t)(cb + tr + p) * 256 + kb + tc] = tile[tc][tr + p];
}

// ---------------- k1: HT = leaky(h @ W), bf16 out [8192][512] ----------------
__global__ void ht_gemm(const float* __restrict__ h, const float* __restrict__ Wt,
                        u16* __restrict__ HT) {
  __shared__ __align__(16) u16 Abuf[128 * 40];
  __shared__ __align__(16) u16 Bbuf[128 * 40];
  int tid = threadIdx.x;
  int cb = blockIdx.x, rb = blockIdx.y;
  int r0 = rb * 128, c0 = cb * 128;
  int lane = tid & 63, wv = tid >> 6;
  int wr = wv >> 1, wc = wv & 1;
  int mrow = lane & 15, q = lane >> 4;
  int ch = tid & 7, m0 = tid >> 3;

  f32x4 acc[4][4];
#pragma unroll
  for (int i = 0; i < 4; i++)
#pragma unroll
    for (int j = 0; j < 4; j++) acc[i][j] = f32x4{0.f, 0.f, 0.f, 0.f};

  for (int kt = 0; kt < 256; kt += 32) {
    __syncthreads();
#pragma unroll
    for (int mp = 0; mp < 128; mp += 32) {
      int m = m0 + mp;
      float4 v = *(const float4*)(&h[(size_t)(r0 + m) * 256 + kt + ch * 4]);
      uint2 p;
      p.x = (u32)f2bf(v.x) | ((u32)f2bf(v.y) << 16);
      p.y = (u32)f2bf(v.z) | ((u32)f2bf(v.w) << 16);
      *(uint2*)(&Abuf[m * 40 + ch * 4]) = p;
      float4 u = *(const float4*)(&Wt[(size_t)(c0 + m) * 256 + kt + ch * 4]);
      uint2 r;
      r.x = (u32)f2bf(u.x) | ((u32)f2bf(u.y) << 16);
      r.y = (u32)f2bf(u.z) | ((u32)f2bf(u.w) << 16);
      *(uint2*)(&Bbuf[m * 40 + ch * 4]) = r;
    }
    __syncthreads();
    bf16x8 af[4], bfv[4];
#pragma unroll
    for (int i = 0; i < 4; i++)
      af[i] = *(const bf16x8*)(&Abuf[(wr * 64 + i * 16 + mrow) * 40 + q * 8]);
#pragma unroll
    for (int j = 0; j < 4; j++)
      bfv[j] = *(const bf16x8*)(&Bbuf[(wc * 64 + j * 16 + mrow) * 40 + q * 8]);
#pragma unroll
    for (int i = 0; i < 4; i++)
#pragma unroll
      for (int j = 0; j < 4; j++)
        acc[i][j] = __builtin_amdgcn_mfma_f32_16x16x32_bf16(af[i], bfv[j], acc[i][j], 0, 0, 0);
  }
#pragma unroll
  for (int i = 0; i < 4; i++)
#pragma unroll
    for (int j = 0; j < 4; j++)
#pragma unroll
      for (int r = 0; r < 4; r++) {
        int gi = r0 + wr * 64 + i * 16 + q * 4 + r;
        int gc = c0 + wc * 64 + j * 16 + mrow;
        float v = acc[i][j][r];
        v = v >= 0.f ? v : 0.1f * v;
        HT[(size_t)gi * 512 + gc] = f2bf(v);
      }
}

// ---------------- k2: build Yt [528][8192] bf16 (32-j slabs, grid 256) -------
__global__ void build_yt(const u16* __restrict__ HT, const float* __restrict__ a,
                         u16* __restrict__ Yt) {
  __shared__ u16 sht[32][528];
  __shared__ float swv[32 * 4];
  __shared__ float sa[512];
  int t = threadIdx.x;
  int j0 = blockIdx.x * 32;
  for (int i = t; i < 512; i += 256) {
    int g = i >> 7, d = i & 127;
    sa[i] = a[g * 256 + 128 + d];
  }
#pragma unroll
  for (int p = 0; p < 8; ++p) {
    int el = t + 256 * p;                 // 2048 uint4 slots: 32 rows x 64
    int row = el >> 6, col8 = el & 63;
    *(uint4*)(&sht[row][col8 * 8]) = *(const uint4*)(&HT[(size_t)(j0 + row) * 512 + col8 * 8]);
  }
  __syncthreads();
  if (t < 128) {
    int jl = t >> 2, g = t & 3;
    float acc = 0.f;
#pragma unroll
    for (int d8 = 0; d8 < 16; ++d8) {
      bf16x8 v = *(const bf16x8*)(&sht[jl][g * 128 + d8 * 8]);
#pragma unroll
      for (int u = 0; u < 8; ++u)
        acc += bf2f((u16)v[u]) * sa[g * 128 + d8 * 8 + u];
    }
    swv[jl * 4 + g] = __expf(acc);
  }
  __syncthreads();
  int oj = (t & 3) * 8, oc = t >> 2;      // 4 j-octets x 64 cols per pass
  for (int pass = 0; pass < 9; ++pass) {
    int c = pass * 64 + oc;
    if (c >= 528) break;
    u32 pk[4] = {0u, 0u, 0u, 0u};
    if (c < 512) {
      int g = c >> 7;
#pragma unroll
      for (int u = 0; u < 4; ++u) {
        int j = oj + 2 * u;
        float v0 = bf2f(sht[j][c]) * swv[j * 4 + g];
        float v1 = bf2f(sht[j + 1][c]) * swv[(j + 1) * 4 + g];
        pk[u] = (u32)f2bf(v0) | ((u32)f2bf(v1) << 16);
      }
    } else if (c < 516) {
      int g = c - 512;
#pragma unroll
      for (int u = 0; u < 4; ++u) {
        int j = oj + 2 * u;
        float v0 = swv[j * 4 + g];
        float v1 = swv[(j + 1) * 4 + g];
        pk[u] = (u32)f2bf(v0) | ((u32)f2bf(v1) << 16);
      }
    }
    *(uint4*)(&Yt[(size_t)c * 8192 + j0 + oj]) = make_uint4(pk[0], pk[1], pk[2], pk[3]);
  }
}

// ---------------- k3: adj GEMM v7 -- 2-ahead GLD16, counted vmcnt ----------
// grid (4, 64) = (kh, rb): XCD = linear%8 in {kh, kh+4} -> each XCD's L2
// holds ONE 2.16 MB Yt quarter. 512 threads = 8 waves (2wr x 4wc).
// Per step t: A(t+1) nt-loads (oldest), GLD16 tile t+2 -> 3rd buffer,
// MFMA tile t, pack A(t+1), s_waitcnt vmcnt(4|5) -- retires tile t+1's
// GLD16s only, tile t+2's loads SURVIVE the barrier (T4).
// XOR swizzle (r1-proven, 0 conflicts): GLD16 global source octet
// bq = (lane&3)^((lane>>3)&3); ds_read slot qs = q^((mrow>>1)&3).
__global__ __launch_bounds__(512) void adj_gemm(const int* __restrict__ adj,
                                                const u16* __restrict__ Yt,
                                                float* __restrict__ C,
                                                float* __restrict__ S) {
  __shared__ __align__(16) u16 Bbuf[3][512 * 32];   // 96 KB
  __shared__ __align__(16) u16 Bden[3][16 * 32];    // 3 KB
  __shared__ __align__(16) u16 Abuf[2][128 * 32];   // 16 KB
  int tid = threadIdx.x;
  int rb = blockIdx.y, kh = blockIdx.x;             // kh fastest -> XCD pin
  int r0 = rb * 128, k0 = kh * 2048;
  int lane = tid & 63, wv = tid >> 6;
  int wr = wv >> 2, wc = wv & 3;
  int mrow = lane & 15, q = lane >> 4;
  int qs = q ^ ((mrow >> 1) & 3);                   // swizzled read slot
  int am = tid >> 2, aq = tid & 3;                  // A staging row / slot
  int asw = am * 32 + ((aq ^ ((am >> 1) & 3)) * 8); // swizzled A store off
  const int* abase = &adj[(size_t)(r0 + am) * 8192 + k0 + aq * 8];
  int brow = lane >> 2;
  int bq = (lane & 3) ^ ((lane >> 3) & 3);          // pre-swizzled src octet
  bool do_den = (wc == 0);

  f32x4 acc[4][8];
#pragma unroll
  for (int i = 0; i < 4; i++)
#pragma unroll
    for (int j = 0; j < 8; j++) acc[i][j] = f32x4{0.f, 0.f, 0.f, 0.f};
  f32x4 accD[4];
#pragma unroll
  for (int i = 0; i < 4; i++) accD[i] = f32x4{0.f, 0.f, 0.f, 0.f};

#define LOADA(V0, V1, TT)                                              \
  {                                                                    \
    const int* ap = abase + (size_t)(TT) * 32;                         \
    V0 = __builtin_nontemporal_load((const i32x4*)(ap));               \
    V1 = __builtin_nontemporal_load((const i32x4*)(ap + 4));           \
  }
#define PACKA(DST, V0, V1)                                             \
  {                                                                    \
    uint4 pk;                                                          \
    pk.x = 16256u * ((u32)V0[0] | ((u32)V0[1] << 16));                 \
    pk.y = 16256u * ((u32)V0[2] | ((u32)V0[3] << 16));                 \
    pk.z = 16256u * ((u32)V1[0] | ((u32)V1[1] << 16));                 \
    pk.w = 16256u * ((u32)V1[2] | ((u32)V1[3] << 16));                 \
    *(uint4*)((DST) + asw) = pk;                                       \
  }
#define STAGE_B(DB, DD, KT)                                            \
  {                                                                    \
    _Pragma("unroll") for (int p = 0; p < 4; ++p)                      \
        GLD16(&Yt[(size_t)(p * 128 + wv * 16 + brow) * 8192 + (KT) + bq * 8], \
              (DB) + (p * 128 + wv * 16) * 32);                        \
    if (wv == 0)                                                       \
      GLD16(&Yt[(size_t)(512 + brow) * 8192 + (KT) + bq * 8], (DD));   \
  }
#define WAIT_KEEP_ONE()                                                \
  {                                                                    \
    if (wv == 0) asm volatile("s_waitcnt vmcnt(5)" ::: "memory");      \
    else         asm volatile("s_waitcnt vmcnt(4)" ::: "memory");      \
  }

  // ---- prologue: A(0) -> Abuf[0]; GLD16 tiles 0,1 -> Bbuf[0],Bbuf[1] ----
  {
    i32x4 a0, a1;
    LOADA(a0, a1, 0);
    __builtin_amdgcn_sched_barrier(0);
    STAGE_B(&Bbuf[0][0], &Bden[0][0], k0);
    STAGE_B(&Bbuf[1][0], &Bden[1][0], k0 + 32);
    PACKA(&Abuf[0][0], a0, a1);     // waits A-loads (oldest); GLD16s remain
    WAIT_KEEP_ONE();                // retire tile0; tile1 stays in flight
    asm volatile("s_waitcnt lgkmcnt(0)" ::: "memory");
    __builtin_amdgcn_s_barrier();
  }

  u16 *bcur = &Bbuf[0][0], *bnxt = &Bbuf[1][0], *bnn = &Bbuf[2][0];
  u16 *dcur = &Bden[0][0], *dnxt = &Bden[1][0], *dnn = &Bden[2][0];

  for (int t = 0; t < 64; ++t) {
    i32x4 v0, v1;
    if (t < 63) {
      LOADA(v0, v1, t + 1);                       // oldest vmem this step
      __builtin_amdgcn_sched_barrier(0);          // keep before GLD16s
    }
    if (t < 62) STAGE_B(bnn, dnn, k0 + (t + 2) * 32);
    // ---- compute tile t ----
    bf16x8 af[4], bfv[8];
    const u16* Ab = &Abuf[t & 1][0];
#pragma unroll
    for (int i = 0; i < 4; i++)
      af[i] = *(const bf16x8*)(&Ab[(wr * 64 + i * 16 + mrow) * 32 + qs * 8]);
#pragma unroll
    for (int j = 0; j < 8; j++)
      bfv[j] = *(const bf16x8*)(&bcur[(wc * 128 + j * 16 + mrow) * 32 + qs * 8]);
    __builtin_amdgcn_s_setprio(1);
#pragma unroll
    for (int i = 0; i < 4; i++)
#pragma unroll
      for (int j = 0; j < 8; j++)
        acc[i][j] = __builtin_amdgcn_mfma_f32_16x16x32_bf16(af[i], bfv[j], acc[i][j], 0, 0, 0);
    if (do_den) {
      bf16x8 bd = *(const bf16x8*)(&dcur[mrow * 32 + qs * 8]);
#pragma unroll
      for (int i = 0; i < 4; i++)
        accD[i] = __builtin_amdgcn_mfma_f32_16x16x32_bf16(af[i], bd, accD[i], 0, 0, 0);
    }
    __builtin_amdgcn_s_setprio(0);
    // ---- finish staging A(t+1) ----
    if (t < 63) PACKA(&Abuf[(t + 1) & 1][0], v0, v1);
    // ---- retire tile t+1's GLD16s; tile t+2's stay in flight ----
    if (t < 62) {
      WAIT_KEEP_ONE();
    } else if (t == 62) {
      asm volatile("s_waitcnt vmcnt(0)" ::: "memory");
    }
    if (t < 63) {
      asm volatile("s_waitcnt lgkmcnt(0)" ::: "memory");
      __builtin_amdgcn_s_barrier();
    }
    u16* tb = bcur; bcur = bnxt; bnxt = bnn; bnn = tb;
    u16* td = dcur; dcur = dnxt; dnxt = dnn; dnn = td;
  }
#undef LOADA
#undef PACKA
#undef STAGE_B
#undef WAIT_KEEP_ONE

  float* Ck = C + (size_t)kh * 8192 * 512;
#pragma unroll
  for (int i = 0; i < 4; i++)
#pragma unroll
    for (int j = 0; j < 8; j++)
#pragma unroll
      for (int r = 0; r < 4; r++) {
        int gi = r0 + wr * 64 + i * 16 + q * 4 + r;
        int gc = wc * 128 + j * 16 + mrow;
        Ck[(size_t)gi * 512 + gc] = acc[i][j][r];
      }
  if (do_den && mrow < 4) {
    float* Sk = S + (size_t)kh * 4 * 8192;
#pragma unroll
    for (int i = 0; i < 4; i++)
#pragma unroll
      for (int r = 0; r < 4; r++) {
        int gi = r0 + wr * 64 + i * 16 + q * 4 + r;
        Sk[(size_t)mrow * 8192 + gi] = accD[i][r];
      }
  }
}

// ---------------- k4: combine K-split + heads ----------------
__global__ void finalize_gat(const float* __restrict__ C, const float* __restrict__ S,
                             float* __restrict__ out) {
  int idx = blockIdx.x * 256 + threadIdx.x;
  int i = idx >> 7, d = idx & 127;
  float s = 0.f;
#pragma unroll
  for (int g = 0; g < 4; ++g) {
    float num = 0.f, den = 0.f;
#pragma unroll
    for (int kh = 0; kh < 4; ++kh) {
      num += C[(size_t)kh * 8192 * 512 + (size_t)i * 512 + g * 128 + d];
      den += S[(size_t)kh * 4 * 8192 + (size_t)g * 8192 + i];
    }
    s += num / den;
  }
  out[idx] = 0.25f * s;
}

extern "C" void kernel_launch(void* const* d_in, const int* in_sizes, int n_in,
                              void* d_out, int out_size, void* d_ws, size_t ws_size,
                              hipStream_t stream) {
  const float* h   = (const float*)d_in[0];
  const int*   adj = (const int*)d_in[1];
  const float* W   = (const float*)d_in[2];
  const float* a   = (const float*)d_in[3];
  float* out = (float*)d_out;
  char* ws = (char*)d_ws;
  // ws: Wt 0.5M | HT 8M | Yt 8.65M | C 64M (4 x 16M) | S 0.5M  (~85 MB)
  float* Wt = (float*)(ws + 0);
  u16*   HT = (u16*)(ws + 524288);
  u16*   Yt = (u16*)(ws + 8912896);
  float* C  = (float*)(ws + 17563648);
  float* S  = (float*)(ws + 84672512);

  transpose_w<<<dim3(16, 8), 256, 0, stream>>>(W, Wt);
  ht_gemm<<<dim3(4, 64), 256, 0, stream>>>(h, Wt, HT);
  build_yt<<<dim3(256), 256, 0, stream>>>(HT, a, Yt);
  adj_gemm<<<dim3(4, 64), 512, 0, stream>>>(adj, Yt, C, S);
  finalize_gat<<<dim3(4096), 256, 0, stream>>>(C, S, out);
}

// Round 14
// 452.319 us; speedup vs baseline: 1.2214x; 1.0057x over previous
//
#include <hip/hip_runtime.h>

// GAT layer, N=8192, H=4, d=128.
// softmax_j(src_i + tgt_j) masked == adj-normalized w_j = exp(tgt_j); src cancels:
//   out[i,d] = 0.25 * sum_h ( (adj @ (w_h*ht_h))[i,d] / (adj @ w_h)[i] )
// Pipeline:
//   k0: Wt = W^T
//   k1: ht_gemm FUSED: leaky(h @ W) AND w=exp(ht.a2) AND Yt write.
//       Block (cb,rb) owns head g=cb's full d-range for 128 rows ->
//       w computed in-register (shfl_xor over mrow + 1KB LDS wave-pair
//       exchange); writes Yt rows g*128+d (w*ht) and 512+g (w) directly.
//       HT buffer and build_yt kernel ELIMINATED. Rows 516..527 unwritten:
//       they only feed discarded den-MFMA output cols 4..15.
//   k3: adj_gemm v7 (session best, r13-verbatim): BM=128, BN=512, 8 waves,
//       grid (4,64) kh->XCD pinned. 2-AHEAD GLD16 staging, triple-buffered
//       B LDS, counted vmcnt(4|5) per step (tile t+2 stays in flight across
//       the barrier). XOR swizzle on A and B. nt adj loads.
//   k4: out = 0.25 * sum_g (sum_kh C_kh)[i,512g+d] / (sum_kh S_kh)[g,i]
// ws ~85 MB: Wt 0.5M | (HT slot unused) | Yt 8.65M | C 64M | S 0.5M

typedef unsigned short u16;
typedef unsigned int u32;
using bf16x8 = __attribute__((ext_vector_type(8))) short;
using f32x4  = __attribute__((ext_vector_type(4))) float;
using i32x4  = __attribute__((ext_vector_type(4))) int;

typedef const void __attribute__((address_space(1))) gas_void;
typedef void __attribute__((address_space(3))) las_void;
#define GLD16(g, l) __builtin_amdgcn_global_load_lds((gas_void*)(g), (las_void*)(l), 16, 0, 0)

__device__ __forceinline__ u16 f2bf(float f) {
  u32 u = __float_as_uint(f);
  return (u16)((u + 0x7FFFu + ((u >> 16) & 1u)) >> 16);  // RNE
}
__device__ __forceinline__ float bf2f(u16 u) {
  return __uint_as_float(((u32)u) << 16);
}

// ---------------- k0: transpose W [256][512] -> Wt [512][256] ----------------
__global__ void transpose_w(const float* __restrict__ W, float* __restrict__ Wt) {
  __shared__ float tile[32][33];
  int cb = blockIdx.x * 32, kb = blockIdx.y * 32;
  int tc = threadIdx.x & 31, tr = threadIdx.x >> 5;
  for (int p = 0; p < 32; p += 8)
    tile[tr + p][tc] = W[(size_t)(kb + tr + p) * 512 + cb + tc];
  __syncthreads();
  for (int p = 0; p < 32; p += 8)
    Wt[(size_t)(cb + tr + p) * 256 + kb + tc] = tile[tc][tr + p];
}

// ---------------- k1: FUSED ht_gemm + build_yt ----------------
// grid (4, 64) = (cb=g, rb). Block computes ht rows r0..r0+127 for head g,
// then w[j] = exp(sum_d leaky(ht)[j,d]*a[g,128+d]) and writes Yt directly:
//   Yt[g*128+d][j] = w[j]*leaky(ht)[j,d]   (bf16, j-contiguous)
//   Yt[512+g][j]   = w[j]
__global__ void ht_gemm(const float* __restrict__ h, const float* __restrict__ Wt,
                        const float* __restrict__ a, u16* __restrict__ Yt) {
  __shared__ __align__(16) u16 Abuf[128 * 40];
  __shared__ __align__(16) u16 Bbuf[128 * 40];
  __shared__ float red[2][2][64];           // [wc][wr][i*16+q*4+r]
  int tid = threadIdx.x;
  int cb = blockIdx.x, rb = blockIdx.y;
  int r0 = rb * 128, c0 = cb * 128;
  int lane = tid & 63, wv = tid >> 6;
  int wr = wv >> 1, wc = wv & 1;
  int mrow = lane & 15, q = lane >> 4;
  int ch = tid & 7, m0 = tid >> 3;

  f32x4 acc[4][4];
#pragma unroll
  for (int i = 0; i < 4; i++)
#pragma unroll
    for (int j = 0; j < 4; j++) acc[i][j] = f32x4{0.f, 0.f, 0.f, 0.f};

  for (int kt = 0; kt < 256; kt += 32) {
    __syncthreads();
#pragma unroll
    for (int mp = 0; mp < 128; mp += 32) {
      int m = m0 + mp;
      float4 v = *(const float4*)(&h[(size_t)(r0 + m) * 256 + kt + ch * 4]);
      uint2 p;
      p.x = (u32)f2bf(v.x) | ((u32)f2bf(v.y) << 16);
      p.y = (u32)f2bf(v.z) | ((u32)f2bf(v.w) << 16);
      *(uint2*)(&Abuf[m * 40 + ch * 4]) = p;
      float4 u = *(const float4*)(&Wt[(size_t)(c0 + m) * 256 + kt + ch * 4]);
      uint2 r;
      r.x = (u32)f2bf(u.x) | ((u32)f2bf(u.y) << 16);
      r.y = (u32)f2bf(u.z) | ((u32)f2bf(u.w) << 16);
      *(uint2*)(&Bbuf[m * 40 + ch * 4]) = r;
    }
    __syncthreads();
    bf16x8 af[4], bfv[4];
#pragma unroll
    for (int i = 0; i < 4; i++)
      af[i] = *(const bf16x8*)(&Abuf[(wr * 64 + i * 16 + mrow) * 40 + q * 8]);
#pragma unroll
    for (int j = 0; j < 4; j++)
      bfv[j] = *(const bf16x8*)(&Bbuf[(wc * 64 + j * 16 + mrow) * 40 + q * 8]);
#pragma unroll
    for (int i = 0; i < 4; i++)
#pragma unroll
      for (int j = 0; j < 4; j++)
        acc[i][j] = __builtin_amdgcn_mfma_f32_16x16x32_bf16(af[i], bfv[j], acc[i][j], 0, 0, 0);
  }

  // ---- epilogue: leaky in place ----
#pragma unroll
  for (int i = 0; i < 4; i++)
#pragma unroll
    for (int jj = 0; jj < 4; jj++)
#pragma unroll
      for (int r = 0; r < 4; r++) {
        float v = acc[i][jj][r];
        acc[i][jj][r] = v >= 0.f ? v : 0.1f * v;
      }
  // ---- per-lane partial dot with a2[d], d = wc*64 + jj*16 + mrow ----
  float a2[4];
#pragma unroll
  for (int jj = 0; jj < 4; jj++)
    a2[jj] = a[cb * 256 + 128 + wc * 64 + jj * 16 + mrow];
  float part[4][4];                        // [i][r] -> j = wr*64+i*16+q*4+r
#pragma unroll
  for (int i = 0; i < 4; i++)
#pragma unroll
    for (int r = 0; r < 4; r++) {
      float s = 0.f;
#pragma unroll
      for (int jj = 0; jj < 4; jj++) s += acc[i][jj][r] * a2[jj];
      part[i][r] = s;
    }
  // ---- reduce across the 16 mrow lanes (same q) ----
#pragma unroll
  for (int mask = 1; mask <= 8; mask <<= 1)
#pragma unroll
    for (int i = 0; i < 4; i++)
#pragma unroll
      for (int r = 0; r < 4; r++)
        part[i][r] += __shfl_xor(part[i][r], mask);
  // ---- exchange across the wc wave pair ----
  if (mrow == 0)
#pragma unroll
    for (int i = 0; i < 4; i++)
#pragma unroll
      for (int r = 0; r < 4; r++)
        red[wc][wr][i * 16 + q * 4 + r] = part[i][r];
  __syncthreads();
  float wexp[4][4];
#pragma unroll
  for (int i = 0; i < 4; i++)
#pragma unroll
    for (int r = 0; r < 4; r++)
      wexp[i][r] = __expf(part[i][r] + red[wc ^ 1][wr][i * 16 + q * 4 + r]);

  // ---- write Yt rows g*128+d = w*ht (4 contiguous-j bf16 per store) ----
#pragma unroll
  for (int i = 0; i < 4; i++) {
    int colb = r0 + wr * 64 + i * 16 + q * 4;
#pragma unroll
    for (int jj = 0; jj < 4; jj++) {
      uint2 pk;
      pk.x = (u32)f2bf(wexp[i][0] * acc[i][jj][0]) |
             ((u32)f2bf(wexp[i][1] * acc[i][jj][1]) << 16);
      pk.y = (u32)f2bf(wexp[i][2] * acc[i][jj][2]) |
             ((u32)f2bf(wexp[i][3] * acc[i][jj][3]) << 16);
      int row = cb * 128 + wc * 64 + jj * 16 + mrow;
      *(uint2*)(&Yt[(size_t)row * 8192 + colb]) = pk;
    }
  }
  // ---- write w row (512+g) ----
  if (wc == 0 && mrow == 0) {
#pragma unroll
    for (int i = 0; i < 4; i++) {
      uint2 pk;
      pk.x = (u32)f2bf(wexp[i][0]) | ((u32)f2bf(wexp[i][1]) << 16);
      pk.y = (u32)f2bf(wexp[i][2]) | ((u32)f2bf(wexp[i][3]) << 16);
      *(uint2*)(&Yt[(size_t)(512 + cb) * 8192 + r0 + wr * 64 + i * 16 + q * 4]) = pk;
    }
  }
}

// ---------------- k3: adj GEMM v7 -- 2-ahead GLD16, counted vmcnt ----------
// grid (4, 64) = (kh, rb): XCD = linear%8 in {kh, kh+4} -> each XCD's L2
// holds ONE 2.16 MB Yt quarter. 512 threads = 8 waves (2wr x 4wc).
// Per step t: A(t+1) nt-loads (oldest), GLD16 tile t+2 -> 3rd buffer,
// MFMA tile t, pack A(t+1), s_waitcnt vmcnt(4|5) -- retires tile t+1's
// GLD16s only, tile t+2's loads SURVIVE the barrier (T4).
// XOR swizzle (r1-proven, 0 conflicts): GLD16 global source octet
// bq = (lane&3)^((lane>>3)&3); ds_read slot qs = q^((mrow>>1)&3).
__global__ __launch_bounds__(512) void adj_gemm(const int* __restrict__ adj,
                                                const u16* __restrict__ Yt,
                                                float* __restrict__ C,
                                                float* __restrict__ S) {
  __shared__ __align__(16) u16 Bbuf[3][512 * 32];   // 96 KB
  __shared__ __align__(16) u16 Bden[3][16 * 32];    // 3 KB
  __shared__ __align__(16) u16 Abuf[2][128 * 32];   // 16 KB
  int tid = threadIdx.x;
  int rb = blockIdx.y, kh = blockIdx.x;             // kh fastest -> XCD pin
  int r0 = rb * 128, k0 = kh * 2048;
  int lane = tid & 63, wv = tid >> 6;
  int wr = wv >> 2, wc = wv & 3;
  int mrow = lane & 15, q = lane >> 4;
  int qs = q ^ ((mrow >> 1) & 3);                   // swizzled read slot
  int am = tid >> 2, aq = tid & 3;                  // A staging row / slot
  int asw = am * 32 + ((aq ^ ((am >> 1) & 3)) * 8); // swizzled A store off
  const int* abase = &adj[(size_t)(r0 + am) * 8192 + k0 + aq * 8];
  int brow = lane >> 2;
  int bq = (lane & 3) ^ ((lane >> 3) & 3);          // pre-swizzled src octet
  bool do_den = (wc == 0);

  f32x4 acc[4][8];
#pragma unroll
  for (int i = 0; i < 4; i++)
#pragma unroll
    for (int j = 0; j < 8; j++) acc[i][j] = f32x4{0.f, 0.f, 0.f, 0.f};
  f32x4 accD[4];
#pragma unroll
  for (int i = 0; i < 4; i++) accD[i] = f32x4{0.f, 0.f, 0.f, 0.f};

#define LOADA(V0, V1, TT)                                              \
  {                                                                    \
    const int* ap = abase + (size_t)(TT) * 32;                         \
    V0 = __builtin_nontemporal_load((const i32x4*)(ap));               \
    V1 = __builtin_nontemporal_load((const i32x4*)(ap + 4));           \
  }
#define PACKA(DST, V0, V1)                                             \
  {                                                                    \
    uint4 pk;                                                          \
    pk.x = 16256u * ((u32)V0[0] | ((u32)V0[1] << 16));                 \
    pk.y = 16256u * ((u32)V0[2] | ((u32)V0[3] << 16));                 \
    pk.z = 16256u * ((u32)V1[0] | ((u32)V1[1] << 16));                 \
    pk.w = 16256u * ((u32)V1[2] | ((u32)V1[3] << 16));                 \
    *(uint4*)((DST) + asw) = pk;                                       \
  }
#define STAGE_B(DB, DD, KT)                                            \
  {                                                                    \
    _Pragma("unroll") for (int p = 0; p < 4; ++p)                      \
        GLD16(&Yt[(size_t)(p * 128 + wv * 16 + brow) * 8192 + (KT) + bq * 8], \
              (DB) + (p * 128 + wv * 16) * 32);                        \
    if (wv == 0)                                                       \
      GLD16(&Yt[(size_t)(512 + brow) * 8192 + (KT) + bq * 8], (DD));   \
  }
#define WAIT_KEEP_ONE()                                                \
  {                                                                    \
    if (wv == 0) asm volatile("s_waitcnt vmcnt(5)" ::: "memory");      \
    else         asm volatile("s_waitcnt vmcnt(4)" ::: "memory");      \
  }

  // ---- prologue: A(0) -> Abuf[0]; GLD16 tiles 0,1 -> Bbuf[0],Bbuf[1] ----
  {
    i32x4 a0, a1;
    LOADA(a0, a1, 0);
    __builtin_amdgcn_sched_barrier(0);
    STAGE_B(&Bbuf[0][0], &Bden[0][0], k0);
    STAGE_B(&Bbuf[1][0], &Bden[1][0], k0 + 32);
    PACKA(&Abuf[0][0], a0, a1);     // waits A-loads (oldest); GLD16s remain
    WAIT_KEEP_ONE();                // retire tile0; tile1 stays in flight
    asm volatile("s_waitcnt lgkmcnt(0)" ::: "memory");
    __builtin_amdgcn_s_barrier();
  }

  u16 *bcur = &Bbuf[0][0], *bnxt = &Bbuf[1][0], *bnn = &Bbuf[2][0];
  u16 *dcur = &Bden[0][0], *dnxt = &Bden[1][0], *dnn = &Bden[2][0];

  for (int t = 0; t < 64; ++t) {
    i32x4 v0, v1;
    if (t < 63) {
      LOADA(v0, v1, t + 1);                       // oldest vmem this step
      __builtin_amdgcn_sched_barrier(0);          // keep before GLD16s
    }
    if (t < 62) STAGE_B(bnn, dnn, k0 + (t + 2) * 32);
    // ---- compute tile t ----
    bf16x8 af[4], bfv[8];
    const u16* Ab = &Abuf[t & 1][0];
#pragma unroll
    for (int i = 0; i < 4; i++)
      af[i] = *(const bf16x8*)(&Ab[(wr * 64 + i * 16 + mrow) * 32 + qs * 8]);
#pragma unroll
    for (int j = 0; j < 8; j++)
      bfv[j] = *(const bf16x8*)(&bcur[(wc * 128 + j * 16 + mrow) * 32 + qs * 8]);
    __builtin_amdgcn_s_setprio(1);
#pragma unroll
    for (int i = 0; i < 4; i++)
#pragma unroll
      for (int j = 0; j < 8; j++)
        acc[i][j] = __builtin_amdgcn_mfma_f32_16x16x32_bf16(af[i], bfv[j], acc[i][j], 0, 0, 0);
    if (do_den) {
      bf16x8 bd = *(const bf16x8*)(&dcur[mrow * 32 + qs * 8]);
#pragma unroll
      for (int i = 0; i < 4; i++)
        accD[i] = __builtin_amdgcn_mfma_f32_16x16x32_bf16(af[i], bd, accD[i], 0, 0, 0);
    }
    __builtin_amdgcn_s_setprio(0);
    // ---- finish staging A(t+1) ----
    if (t < 63) PACKA(&Abuf[(t + 1) & 1][0], v0, v1);
    // ---- retire tile t+1's GLD16s; tile t+2's stay in flight ----
    if (t < 62) {
      WAIT_KEEP_ONE();
    } else if (t == 62) {
      asm volatile("s_waitcnt vmcnt(0)" ::: "memory");
    }
    if (t < 63) {
      asm volatile("s_waitcnt lgkmcnt(0)" ::: "memory");
      __builtin_amdgcn_s_barrier();
    }
    u16* tb = bcur; bcur = bnxt; bnxt = bnn; bnn = tb;
    u16* td = dcur; dcur = dnxt; dnxt = dnn; dnn = td;
  }
#undef LOADA
#undef PACKA
#undef STAGE_B
#undef WAIT_KEEP_ONE

  float* Ck = C + (size_t)kh * 8192 * 512;
#pragma unroll
  for (int i = 0; i < 4; i++)
#pragma unroll
    for (int j = 0; j < 8; j++)
#pragma unroll
      for (int r = 0; r < 4; r++) {
        int gi = r0 + wr * 64 + i * 16 + q * 4 + r;
        int gc = wc * 128 + j * 16 + mrow;
        Ck[(size_t)gi * 512 + gc] = acc[i][j][r];
      }
  if (do_den && mrow < 4) {
    float* Sk = S + (size_t)kh * 4 * 8192;
#pragma unroll
    for (int i = 0; i < 4; i++)
#pragma unroll
      for (int r = 0; r < 4; r++) {
        int gi = r0 + wr * 64 + i * 16 + q * 4 + r;
        Sk[(size_t)mrow * 8192 + gi] = accD[i][r];
      }
  }
}

// ---------------- k4: combine K-split + heads ----------------
__global__ void finalize_gat(const float* __restrict__ C, const float* __restrict__ S,
                             float* __restrict__ out) {
  int idx = blockIdx.x * 256 + threadIdx.x;
  int i = idx >> 7, d = idx & 127;
  float s = 0.f;
#pragma unroll
  for (int g = 0; g < 4; ++g) {
    float num = 0.f, den = 0.f;
#pragma unroll
    for (int kh = 0; kh < 4; ++kh) {
      num += C[(size_t)kh * 8192 * 512 + (size_t)i * 512 + g * 128 + d];
      den += S[(size_t)kh * 4 * 8192 + (size_t)g * 8192 + i];
    }
    s += num / den;
  }
  out[idx] = 0.25f * s;
}

extern "C" void kernel_launch(void* const* d_in, const int* in_sizes, int n_in,
                              void* d_out, int out_size, void* d_ws, size_t ws_size,
                              hipStream_t stream) {
  const float* h   = (const float*)d_in[0];
  const int*   adj = (const int*)d_in[1];
  const float* W   = (const float*)d_in[2];
  const float* a   = (const float*)d_in[3];
  float* out = (float*)d_out;
  char* ws = (char*)d_ws;
  // ws: Wt 0.5M | (old HT slot unused) | Yt 8.65M | C 64M (4 x 16M) | S 0.5M
  float* Wt = (float*)(ws + 0);
  u16*   Yt = (u16*)(ws + 8912896);
  float* C  = (float*)(ws + 17563648);
  float* S  = (float*)(ws + 84672512);

  transpose_w<<<dim3(16, 8), 256, 0, stream>>>(W, Wt);
  ht_gemm<<<dim3(4, 64), 256, 0, stream>>>(h, Wt, a, Yt);
  adj_gemm<<<dim3(4, 64), 512, 0, stream>>>(adj, Yt, C, S);
  finalize_gat<<<dim3(4096), 256, 0, stream>>>(C, S, out);
}